// Round 16
// baseline (133.877 us; speedup 1.0000x reference)
//
#include <hip/hip_runtime.h>
#include <hip/hip_bf16.h>

typedef __attribute__((ext_vector_type(8))) short short8;
typedef __attribute__((ext_vector_type(4))) float f32x4;
typedef __attribute__((ext_vector_type(4))) unsigned int u32x4;
typedef unsigned long long u64;
typedef unsigned short u16;
typedef unsigned int u32;

#define NODES 512
#define HIDDEN 512
#define NEDGES 16384

// qkv fragment regions (u16 offsets)
#define KOFF ((size_t)384 * 32 * 2 * 512)          // 12582912
#define VOFF ((size_t)2 * 384 * 32 * 2 * 512)      // 25165824

// ---- helpers ----
static __device__ __forceinline__ u16 f2bf(float f) {
  unsigned u = __float_as_uint(f);
  u += 0x7FFFu + ((u >> 16) & 1u);
  return (u16)(u >> 16);
}

static __device__ __forceinline__ void gld_lds16(const void* g, void* l) {
  __builtin_amdgcn_global_load_lds(
      (const __attribute__((address_space(1))) unsigned int*)g,
      (__attribute__((address_space(3))) unsigned int*)l, 16, 0, 0);
}

// ---- kernel 1: fused fp32 -> bf16 cast of x and the 3 weight matrices ----
__global__ void cast_all(const float* __restrict__ x, const float* __restrict__ wq,
                         const float* __restrict__ wk, const float* __restrict__ wv,
                         u16* __restrict__ xb, u16* __restrict__ wb) {
  const int n4 = 3145728 + 196608;
  int stride = gridDim.x * blockDim.x;
  for (int i = blockIdx.x * blockDim.x + threadIdx.x; i < n4; i += stride) {
    float4 v;
    u16* dst;
    int di;
    if (i < 3145728) {
      v = reinterpret_cast<const float4*>(x)[i];
      dst = xb; di = i;
    } else {
      int t = i - 3145728;
      const float* src = (t < 65536) ? wq : (t < 131072) ? wk : wv;
      v = reinterpret_cast<const float4*>(src)[t & 65535];
      dst = wb; di = t;
    }
    ushort4 o;
    o.x = f2bf(v.x); o.y = f2bf(v.y); o.z = f2bf(v.z); o.w = f2bf(v.w);
    reinterpret_cast<ushort4*>(dst)[di] = o;
  }
}

// ---- kernel 2: edges -> AND-word mask fragments (one atomicOr per edge) ----
__global__ void edge_mf(const int* __restrict__ e, u32* __restrict__ mf) {
  int i = blockIdx.x * 256 + threadIdx.x;
  if (i < NEDGES) {
    int q = e[i];
    int key = e[NEDGES + i];
    int lane = ((key >> 3) & 3) * 16 + (q & 15);
    int idx = (((q >> 4) * 8 + (key >> 6)) * 2 + ((key >> 5) & 1)) * 256
            + lane * 4 + ((key >> 1) & 3);
    atomicOr(&mf[idx], 0xFFFFu << ((key & 1) * 16));
  }
}

// ---- kernel 3: fused QKV GEMM — FROZEN (best-known, 55us) ----
// Double-buffer + counted vmcnt(8), T2 swizzle (conflicts 0), nz-fastest
// block order (FETCH = 25MB ideal). Do not restructure (7 variants tried).
__global__ __launch_bounds__(256, 2)
void qkv_gemm(const u16* __restrict__ xb, const u16* __restrict__ wb,
              const float* __restrict__ bq, const float* __restrict__ bk,
              const float* __restrict__ bv, u16* __restrict__ qkv) {
  __shared__ u16 As[2][128 * 64];
  __shared__ u16 Bs[2][128 * 64];

  const int blk = blockIdx.x;
  const int xcd = blk & 7;
  const int i = blk >> 3;            // 0..287
  const int m0 = (xcd * 24 + i / 12) * 128;
  const int r12 = i % 12;            // nz fastest: A-panel sharers adjacent
  const int z = r12 >> 2;
  const int n0 = (r12 & 3) * 128;

  const u16* Wz = wb + (size_t)z * (512 * 512);
  const float* bias = (z == 0) ? bq : (z == 1) ? bk : bv;

  const int tid = threadIdx.x;
  const int lane = tid & 63;
  const int w = tid >> 6;
  const int wr = w >> 1, wc = w & 1;
  const int l = lane & 15, j = lane >> 4;
  const int sl = l & 7;                           // row&7 for swizzled reads
  const int kb = ((lane & 7) ^ (lane >> 3)) * 16; // pre-swizzled source col

#define STAGE(bb, kt_) do {                                                     \
    const int k0_ = (kt_) * 64;                                                 \
    _Pragma("unroll")                                                           \
    for (int t_ = 0; t_ < 4; ++t_) {                                            \
      int c_ = w * 4 + t_;                                                      \
      int row_ = c_ * 8 + (lane >> 3);                                          \
      gld_lds16((const char*)xb + ((size_t)(m0 + row_) * 512 + k0_) * 2 + kb,   \
                (char*)&As[bb][0] + c_ * 1024);                                 \
      gld_lds16((const char*)Wz + ((size_t)(n0 + row_) * 512 + k0_) * 2 + kb,   \
                (char*)&Bs[bb][0] + c_ * 1024);                                 \
    }                                                                           \
  } while (0)

  f32x4 acc[4][4] = {};

  STAGE(0, 0);
  int cur = 0;

  for (int kt = 0; kt < 8; ++kt) {
    if (kt < 7) {
      STAGE(cur ^ 1, kt + 1);   // 8 more loads in flight (next tile)
      asm volatile("s_waitcnt vmcnt(8)" ::: "memory");  // own buf[cur] loads done
    } else {
      asm volatile("s_waitcnt vmcnt(0)" ::: "memory");  // last tile: full drain
    }
    __builtin_amdgcn_s_barrier();   // collective: buf[cur] fully written

#pragma unroll
    for (int kk = 0; kk < 2; ++kk) {
      short8 a[4], b[4];
#pragma unroll
      for (int mi = 0; mi < 4; ++mi)
        a[mi] = *(const short8*)(&As[cur][0] + (wr * 64 + mi * 16 + l) * 64 +
                                 (((kk * 4 + j) ^ sl) * 8));
#pragma unroll
      for (int ni = 0; ni < 4; ++ni)
        b[ni] = *(const short8*)(&Bs[cur][0] + (wc * 64 + ni * 16 + l) * 64 +
                                 (((kk * 4 + j) ^ sl) * 8));
      if (z == 2) {
#pragma unroll
        for (int mi = 0; mi < 4; ++mi)
#pragma unroll
          for (int ni = 0; ni < 4; ++ni)
            acc[mi][ni] = __builtin_amdgcn_mfma_f32_16x16x32_bf16(a[mi], b[ni], acc[mi][ni], 0, 0, 0);
      } else {
#pragma unroll
        for (int mi = 0; mi < 4; ++mi)
#pragma unroll
          for (int ni = 0; ni < 4; ++ni)
            acc[mi][ni] = __builtin_amdgcn_mfma_f32_16x16x32_bf16(b[ni], a[mi], acc[mi][ni], 0, 0, 0);
      }
    }

    if (kt < 7) {
      asm volatile("s_waitcnt lgkmcnt(0)" ::: "memory");
      __builtin_amdgcn_s_barrier();
    }
    cur ^= 1;
  }
#undef STAGE

  const int bs = m0 >> 9;
  const int hh = (n0 >> 6) + wc;
  const int bh = bs * 8 + hh;

  if (z == 2) {
    // unswapped: col l -> d (dd = ni*16+l), rows j*4+r -> key
    const int ktb = ((m0 & 511) >> 6) + wr;
#pragma unroll
    for (int ni = 0; ni < 4; ++ni) {
      int jcol = n0 + wc * 64 + ni * 16 + l;
      float bv_ = bias[jcol];
      int ds = ni;
#pragma unroll
      for (int mi = 0; mi < 4; ++mi) {
        int kk2 = mi >> 1, oct = ((mi & 1) << 1) | (j >> 1);
        ushort4 pk;
#pragma unroll
        for (int r = 0; r < 4; ++r) pk[r] = f2bf(acc[mi][ni][r] + bv_);
        size_t idx = VOFF + (((((size_t)bh * 8 + ktb) * 2 + kk2) * 4 + ds) * 512)
                   + (oct * 16 + l) * 8 + (j & 1) * 4;
        *reinterpret_cast<ushort4*>(qkv + idx) = pk;
      }
    }
  } else {
    // swapped: rows j*4+r -> d (dd = ni*16+j*4+r), col l -> node
#pragma unroll
    for (int ni = 0; ni < 4; ++ni) {
      int n_base = n0 + wc * 64 + ni * 16 + j * 4;
      float4 b4 = *reinterpret_cast<const float4*>(bias + n_base);
      int kk = ni >> 1, oct = ((ni & 1) << 1) | (j >> 1);
#pragma unroll
      for (int mi = 0; mi < 4; ++mi) {
        ushort4 pk;
#pragma unroll
        for (int r = 0; r < 4; ++r) pk[r] = f2bf(acc[mi][ni][r] + (&b4.x)[r]);
        size_t idx;
        if (z == 0) {
          int qsg = ((m0 & 511) >> 4) + wr * 4 + mi;
          idx = ((((size_t)bh * 32 + qsg) * 2 + kk) * 512) + (oct * 16 + l) * 8 + (j & 1) * 4;
        } else {
          int ktb = ((m0 & 511) >> 6) + wr;
          idx = KOFF + (((((size_t)bh * 8 + ktb) * 4 + mi) * 2 + kk) * 512)
              + (oct * 16 + l) * 8 + (j & 1) * 4;
        }
        *reinterpret_cast<ushort4*>(qkv + idx) = pk;
      }
    }
  }
}

// ---- kernel 4: masked attention — qs=4 (64 q-rows/wave) ----
// ROUND 16: 2x arithmetic intensity — same 12 K/V frag loads per phase now
// feed 36 MFMAs (4 q-subtiles). Grid 768 (3 blocks/CU). 4 independent qs
// chains per phase = 2x ILP for latency hiding. (256,1): no regalloc floor
// above need (round-5 lesson: high floors force spill; floor=1 is safe).
// PV swapped (C[d][q]) -> 16 aligned float4 stores; osum=mfma(ones,pa):
// every reg of lane l = row-sum for q=l.
__global__ __launch_bounds__(256, 1)
void attn_kernel(const u16* __restrict__ qkv, const u32* __restrict__ mf,
                 float* __restrict__ out) {
  const int blk = blockIdx.x;
  const int xcd = blk & 7;
  const int i = blk >> 3;                 // 0..95
  const int bh = xcd * 48 + (i >> 1);
  const int qhalf = i & 1;
  const int bs = bh >> 3, h = bh & 7;
  const int tid = threadIdx.x;
  const int lane = tid & 63;
  const int w = tid >> 6;
  const int l = lane & 15, j = lane >> 4;
  const int qb = qhalf * 16 + w * 4;      // qsg base (4 subtiles per wave)

  // Q fragments, held all kernel
  short8 qf[4][2];
#pragma unroll
  for (int qs = 0; qs < 4; ++qs)
#pragma unroll
    for (int kk = 0; kk < 2; ++kk)
      qf[qs][kk] = *(const short8*)(qkv + (((size_t)bh * 32 + qb + qs) * 2 + kk) * 512 + lane * 8);

  // phase-walking pointers (strength-reduced; frag offsets are immediates)
  const u16* Kp = qkv + KOFF + (size_t)bh * 32768 + lane * 8;
  const u16* Vp = qkv + VOFF + (size_t)bh * 32768 + lane * 8;
  const u32* Mb = mf + qb * 4096 + lane * 4;

  f32x4 o[4][4] = {};
  f32x4 osum[4] = {};
  short8 ones;
#pragma unroll
  for (int t = 0; t < 8; ++t) ones[t] = (short)0x3F80;  // bf16 1.0

#pragma unroll 1
  for (int p = 0; p < 16; ++p) {
    // K fragments (2 ks-subtiles x 2 kk) and V fragments (4 d-subtiles),
    // loaded ONCE per phase, consumed by 4 q-subtiles.
    short8 kf2[2][2];
#pragma unroll
    for (int lks = 0; lks < 2; ++lks)
#pragma unroll
      for (int kk = 0; kk < 2; ++kk)
        kf2[lks][kk] = *(const short8*)(Kp + (lks * 2 + kk) * 512);
    short8 vf[4];
#pragma unroll
    for (int ds = 0; ds < 4; ++ds)
      vf[ds] = *(const short8*)(Vp + ds * 512);

#pragma unroll
    for (int qs = 0; qs < 4; ++qs) {
      // mask loaded per-qs (one u32x4 live at a time)
      u32x4 am = *reinterpret_cast<const u32x4*>(Mb + qs * 4096);

      // QK^T: col l = q, row j*4+r = key-in-16 of subtile lks
      f32x4 st[2] = {};
#pragma unroll
      for (int lks = 0; lks < 2; ++lks)
#pragma unroll
        for (int kk = 0; kk < 2; ++kk)
          st[lks] = __builtin_amdgcn_mfma_f32_16x16x32_bf16(
              kf2[lks][kk], qf[qs][kk], st[lks], 0, 0, 0);

      // P = exp2(s*log2e/8) (unmasked; scores bounded), pack to bf16
      float pr[8];
#pragma unroll
      for (int lks = 0; lks < 2; ++lks)
#pragma unroll
        for (int r = 0; r < 4; ++r)
          pr[lks * 4 + r] = __builtin_exp2f(st[lks][r] * 0.18033688f);
      u32 X0, X1, Y0, Y1;
      asm("v_cvt_pk_bf16_f32 %0, %1, %2" : "=v"(X0) : "v"(pr[0]), "v"(pr[1]));
      asm("v_cvt_pk_bf16_f32 %0, %1, %2" : "=v"(X1) : "v"(pr[2]), "v"(pr[3]));
      asm("v_cvt_pk_bf16_f32 %0, %1, %2" : "=v"(Y0) : "v"(pr[4]), "v"(pr[5]));
      asm("v_cvt_pk_bf16_f32 %0, %1, %2" : "=v"(Y1) : "v"(pr[6]), "v"(pr[7]));
      asm("v_permlane32_swap_b32 %0, %1" : "+v"(X0), "+v"(Y0));
      asm("v_permlane32_swap_b32 %0, %1" : "+v"(X1), "+v"(Y1));
      asm("v_permlane16_swap_b32 %0, %1" : "+v"(X0), "+v"(Y0));
      asm("v_permlane16_swap_b32 %0, %1" : "+v"(X1), "+v"(Y1));
      // mask: AND in the A-frag layout (zeroes masked-out keys exactly)
      u32x4 paw;
      paw[0] = X0 & am[0];
      paw[1] = X1 & am[1];
      paw[2] = Y0 & am[2];
      paw[3] = Y1 & am[3];
      short8 pa = __builtin_bit_cast(short8, paw);
      // row-sum on the MFMA pipe: C[*][q] — every reg of lane l = sum(q=l)
      osum[qs] = __builtin_amdgcn_mfma_f32_16x16x32_bf16(ones, pa, osum[qs], 0, 0, 0);
      // PV swapped: C[d][q] — col l = q, rows = 4 consecutive d per lane
#pragma unroll
      for (int ds = 0; ds < 4; ++ds)
        o[qs][ds] = __builtin_amdgcn_mfma_f32_16x16x32_bf16(vf[ds], pa, o[qs][ds], 0, 0, 0);
    }

    Kp += 2048; Vp += 2048; Mb += 256;
  }

  // epilogue: single inv per lane (q = l), aligned float4 stores
#pragma unroll
  for (int qs = 0; qs < 4; ++qs) {
    float inv = 1.0f / osum[qs][0];
    int node = (qb + qs) * 16 + l;
    float* ob = out + (size_t)bs * 262144 + (size_t)node * 512 + h * 64 + j * 4;
#pragma unroll
    for (int ds = 0; ds < 4; ++ds) {
      float4 v4;
      v4.x = o[qs][ds][0] * inv;
      v4.y = o[qs][ds][1] * inv;
      v4.z = o[qs][ds][2] * inv;
      v4.w = o[qs][ds][3] * inv;
      *reinterpret_cast<float4*>(ob + ds * 16) = v4;
    }
  }
}

// ---- launcher ----
extern "C" void kernel_launch(void* const* d_in, const int* in_sizes, int n_in,
                              void* d_out, int out_size, void* d_ws, size_t ws_size,
                              hipStream_t stream) {
  const float* x  = (const float*)d_in[0];
  const int*   e  = (const int*)d_in[1];
  const float* Wq = (const float*)d_in[2];
  const float* bq = (const float*)d_in[3];
  const float* Wk = (const float*)d_in[4];
  const float* bk = (const float*)d_in[5];
  const float* Wv = (const float*)d_in[6];
  const float* bv = (const float*)d_in[7];
  float* out = (float*)d_out;

  char* ws = (char*)d_ws;
  u16* xb   = (u16*)(ws);                 // 24576*512 bf16 = 25165824 B
  u16* wb   = (u16*)(ws + 25165824);      // 3*512*512 bf16 = 1572864 B
  u16* qkv  = (u16*)(ws + 26738688);      // 3*384*512*64 bf16 = 75497472 B
  u32* mfr  = (u32*)(ws + 102236160);     // 131072 u32 = 524288 B

  hipMemsetAsync(mfr, 0, 524288, stream);
  edge_mf<<<(NEDGES + 255) / 256, 256, 0, stream>>>(e, mfr);

  cast_all<<<2048, 256, 0, stream>>>(x, Wq, Wk, Wv, xb, wb);

  qkv_gemm<<<2304, 256, 0, stream>>>(xb, wb, bq, bk, bv, qkv);
  attn_kernel<<<768, 256, 0, stream>>>(qkv, mfr, out);
}

// Round 17
// 120.067 us; speedup vs baseline: 1.1150x; 1.1150x over previous
//
#include <hip/hip_runtime.h>
#include <hip/hip_bf16.h>

typedef __attribute__((ext_vector_type(8))) short short8;
typedef __attribute__((ext_vector_type(4))) float f32x4;
typedef __attribute__((ext_vector_type(4))) unsigned int u32x4;
typedef unsigned long long u64;
typedef unsigned short u16;
typedef unsigned int u32;

#define NODES 512
#define HIDDEN 512
#define NEDGES 16384

// qkv fragment regions (u16 offsets)
#define KOFF ((size_t)384 * 32 * 2 * 512)          // 12582912
#define VOFF ((size_t)2 * 384 * 32 * 2 * 512)      // 25165824

// ---- helpers ----
static __device__ __forceinline__ u16 f2bf(float f) {
  unsigned u = __float_as_uint(f);
  u += 0x7FFFu + ((u >> 16) & 1u);
  return (u16)(u >> 16);
}

static __device__ __forceinline__ void gld_lds16(const void* g, void* l) {
  __builtin_amdgcn_global_load_lds(
      (const __attribute__((address_space(1))) unsigned int*)g,
      (__attribute__((address_space(3))) unsigned int*)l, 16, 0, 0);
}

// ---- kernel 1: fused fp32 -> bf16 cast of x and the 3 weight matrices ----
__global__ void cast_all(const float* __restrict__ x, const float* __restrict__ wq,
                         const float* __restrict__ wk, const float* __restrict__ wv,
                         u16* __restrict__ xb, u16* __restrict__ wb) {
  const int n4 = 3145728 + 196608;
  int stride = gridDim.x * blockDim.x;
  for (int i = blockIdx.x * blockDim.x + threadIdx.x; i < n4; i += stride) {
    float4 v;
    u16* dst;
    int di;
    if (i < 3145728) {
      v = reinterpret_cast<const float4*>(x)[i];
      dst = xb; di = i;
    } else {
      int t = i - 3145728;
      const float* src = (t < 65536) ? wq : (t < 131072) ? wk : wv;
      v = reinterpret_cast<const float4*>(src)[t & 65535];
      dst = wb; di = t;
    }
    ushort4 o;
    o.x = f2bf(v.x); o.y = f2bf(v.y); o.z = f2bf(v.z); o.w = f2bf(v.w);
    reinterpret_cast<ushort4*>(dst)[di] = o;
  }
}

// ---- kernel 2: edges -> AND-word mask fragments (one atomicOr per edge) ----
__global__ void edge_mf(const int* __restrict__ e, u32* __restrict__ mf) {
  int i = blockIdx.x * 256 + threadIdx.x;
  if (i < NEDGES) {
    int q = e[i];
    int key = e[NEDGES + i];
    int lane = ((key >> 3) & 3) * 16 + (q & 15);
    int idx = (((q >> 4) * 8 + (key >> 6)) * 2 + ((key >> 5) & 1)) * 256
            + lane * 4 + ((key >> 1) & 3);
    atomicOr(&mf[idx], 0xFFFFu << ((key & 1) * 16));
  }
}

// ---- kernel 3: fused QKV GEMM — FROZEN (best-known, 55us) ----
// Double-buffer + counted vmcnt(8), T2 swizzle (conflicts 0), nz-fastest
// block order (FETCH = 25MB ideal). 7 structural variants tried; this won.
__global__ __launch_bounds__(256, 2)
void qkv_gemm(const u16* __restrict__ xb, const u16* __restrict__ wb,
              const float* __restrict__ bq, const float* __restrict__ bk,
              const float* __restrict__ bv, u16* __restrict__ qkv) {
  __shared__ u16 As[2][128 * 64];
  __shared__ u16 Bs[2][128 * 64];

  const int blk = blockIdx.x;
  const int xcd = blk & 7;
  const int i = blk >> 3;            // 0..287
  const int m0 = (xcd * 24 + i / 12) * 128;
  const int r12 = i % 12;            // nz fastest: A-panel sharers adjacent
  const int z = r12 >> 2;
  const int n0 = (r12 & 3) * 128;

  const u16* Wz = wb + (size_t)z * (512 * 512);
  const float* bias = (z == 0) ? bq : (z == 1) ? bk : bv;

  const int tid = threadIdx.x;
  const int lane = tid & 63;
  const int w = tid >> 6;
  const int wr = w >> 1, wc = w & 1;
  const int l = lane & 15, j = lane >> 4;
  const int sl = l & 7;                           // row&7 for swizzled reads
  const int kb = ((lane & 7) ^ (lane >> 3)) * 16; // pre-swizzled source col

#define STAGE(bb, kt_) do {                                                     \
    const int k0_ = (kt_) * 64;                                                 \
    _Pragma("unroll")                                                           \
    for (int t_ = 0; t_ < 4; ++t_) {                                            \
      int c_ = w * 4 + t_;                                                      \
      int row_ = c_ * 8 + (lane >> 3);                                          \
      gld_lds16((const char*)xb + ((size_t)(m0 + row_) * 512 + k0_) * 2 + kb,   \
                (char*)&As[bb][0] + c_ * 1024);                                 \
      gld_lds16((const char*)Wz + ((size_t)(n0 + row_) * 512 + k0_) * 2 + kb,   \
                (char*)&Bs[bb][0] + c_ * 1024);                                 \
    }                                                                           \
  } while (0)

  f32x4 acc[4][4] = {};

  STAGE(0, 0);
  int cur = 0;

  for (int kt = 0; kt < 8; ++kt) {
    if (kt < 7) {
      STAGE(cur ^ 1, kt + 1);   // 8 more loads in flight (next tile)
      asm volatile("s_waitcnt vmcnt(8)" ::: "memory");  // own buf[cur] loads done
    } else {
      asm volatile("s_waitcnt vmcnt(0)" ::: "memory");  // last tile: full drain
    }
    __builtin_amdgcn_s_barrier();   // collective: buf[cur] fully written

#pragma unroll
    for (int kk = 0; kk < 2; ++kk) {
      short8 a[4], b[4];
#pragma unroll
      for (int mi = 0; mi < 4; ++mi)
        a[mi] = *(const short8*)(&As[cur][0] + (wr * 64 + mi * 16 + l) * 64 +
                                 (((kk * 4 + j) ^ sl) * 8));
#pragma unroll
      for (int ni = 0; ni < 4; ++ni)
        b[ni] = *(const short8*)(&Bs[cur][0] + (wc * 64 + ni * 16 + l) * 64 +
                                 (((kk * 4 + j) ^ sl) * 8));
      if (z == 2) {
#pragma unroll
        for (int mi = 0; mi < 4; ++mi)
#pragma unroll
          for (int ni = 0; ni < 4; ++ni)
            acc[mi][ni] = __builtin_amdgcn_mfma_f32_16x16x32_bf16(a[mi], b[ni], acc[mi][ni], 0, 0, 0);
      } else {
#pragma unroll
        for (int mi = 0; mi < 4; ++mi)
#pragma unroll
          for (int ni = 0; ni < 4; ++ni)
            acc[mi][ni] = __builtin_amdgcn_mfma_f32_16x16x32_bf16(b[ni], a[mi], acc[mi][ni], 0, 0, 0);
      }
    }

    if (kt < 7) {
      asm volatile("s_waitcnt lgkmcnt(0)" ::: "memory");
      __builtin_amdgcn_s_barrier();
    }
    cur ^= 1;
  }
#undef STAGE

  const int bs = m0 >> 9;
  const int hh = (n0 >> 6) + wc;
  const int bh = bs * 8 + hh;

  if (z == 2) {
    // unswapped: col l -> d (dd = ni*16+l), rows j*4+r -> key
    const int ktb = ((m0 & 511) >> 6) + wr;
#pragma unroll
    for (int ni = 0; ni < 4; ++ni) {
      int jcol = n0 + wc * 64 + ni * 16 + l;
      float bv_ = bias[jcol];
      int ds = ni;
#pragma unroll
      for (int mi = 0; mi < 4; ++mi) {
        int kk2 = mi >> 1, oct = ((mi & 1) << 1) | (j >> 1);
        ushort4 pk;
#pragma unroll
        for (int r = 0; r < 4; ++r) pk[r] = f2bf(acc[mi][ni][r] + bv_);
        size_t idx = VOFF + (((((size_t)bh * 8 + ktb) * 2 + kk2) * 4 + ds) * 512)
                   + (oct * 16 + l) * 8 + (j & 1) * 4;
        *reinterpret_cast<ushort4*>(qkv + idx) = pk;
      }
    }
  } else {
    // swapped: rows j*4+r -> d (dd = ni*16+j*4+r), col l -> node
#pragma unroll
    for (int ni = 0; ni < 4; ++ni) {
      int n_base = n0 + wc * 64 + ni * 16 + j * 4;
      float4 b4 = *reinterpret_cast<const float4*>(bias + n_base);
      int kk = ni >> 1, oct = ((ni & 1) << 1) | (j >> 1);
#pragma unroll
      for (int mi = 0; mi < 4; ++mi) {
        ushort4 pk;
#pragma unroll
        for (int r = 0; r < 4; ++r) pk[r] = f2bf(acc[mi][ni][r] + (&b4.x)[r]);
        size_t idx;
        if (z == 0) {
          int qsg = ((m0 & 511) >> 4) + wr * 4 + mi;
          idx = ((((size_t)bh * 32 + qsg) * 2 + kk) * 512) + (oct * 16 + l) * 8 + (j & 1) * 4;
        } else {
          int ktb = ((m0 & 511) >> 6) + wr;
          idx = KOFF + (((((size_t)bh * 8 + ktb) * 4 + mi) * 2 + kk) * 512)
              + (oct * 16 + l) * 8 + (j & 1) * 4;
        }
        *reinterpret_cast<ushort4*>(qkv + idx) = pk;
      }
    }
  }
}

// ---- kernel 4: masked attention — qs=2, fragment-direct (best-known) ----
// Frozen round-14 state: no LDS, no barriers, mask as prebuilt AND-words,
// strength-reduced phase pointers, osum via P x ones MFMA. qs=4 regressed
// (VALU-chain + TLP bound: fewer waves, same serial softmax chain);
// PV-swap epilogue was flat.
__global__ __launch_bounds__(256, 2)
void attn_kernel(const u16* __restrict__ qkv, const u32* __restrict__ mf,
                 float* __restrict__ out) {
  const int blk = blockIdx.x;
  const int xcd = blk & 7;
  const int i = blk >> 3;                 // 0..191
  const int bh = xcd * 48 + (i >> 2);
  const int qq = i & 3;
  const int bs = bh >> 3, h = bh & 7;
  const int tid = threadIdx.x;
  const int lane = tid & 63;
  const int w = tid >> 6;
  const int l = lane & 15, j = lane >> 4;
  const int qb = qq * 8 + w * 2;          // qsg base (2 subtiles per wave)

  // Q fragments, held all kernel
  short8 qf[2][2];
#pragma unroll
  for (int qs = 0; qs < 2; ++qs)
#pragma unroll
    for (int kk = 0; kk < 2; ++kk)
      qf[qs][kk] = *(const short8*)(qkv + (((size_t)bh * 32 + qb + qs) * 2 + kk) * 512 + lane * 8);

  // phase-walking pointers (strength-reduced; frag offsets are immediates)
  const u16* Kp = qkv + KOFF + (size_t)bh * 32768 + lane * 8;
  const u16* Vp = qkv + VOFF + (size_t)bh * 32768 + lane * 8;
  const u32* M0 = mf + (qb + 0) * 4096 + lane * 4;
  const u32* M1 = mf + (qb + 1) * 4096 + lane * 4;

  f32x4 o[2][4] = {};
  f32x4 osum[2] = {};
  short8 ones;
#pragma unroll
  for (int t = 0; t < 8; ++t) ones[t] = (short)0x3F80;  // bf16 1.0

#pragma unroll 1
  for (int p = 0; p < 16; ++p) {
    // K fragments (2 ks-subtiles x 2 kk) and V fragments (4 d-subtiles)
    short8 kf2[2][2];
#pragma unroll
    for (int lks = 0; lks < 2; ++lks)
#pragma unroll
      for (int kk = 0; kk < 2; ++kk)
        kf2[lks][kk] = *(const short8*)(Kp + (lks * 2 + kk) * 512);
    short8 vf[4];
#pragma unroll
    for (int ds = 0; ds < 4; ++ds)
      vf[ds] = *(const short8*)(Vp + ds * 512);
    u32x4 am0 = *reinterpret_cast<const u32x4*>(M0);
    u32x4 am1 = *reinterpret_cast<const u32x4*>(M1);

#pragma unroll
    for (int qs = 0; qs < 2; ++qs) {
      // QK^T: col l = q, row j*4+r = key-in-16 of subtile lks
      f32x4 st[2] = {};
#pragma unroll
      for (int lks = 0; lks < 2; ++lks)
#pragma unroll
        for (int kk = 0; kk < 2; ++kk)
          st[lks] = __builtin_amdgcn_mfma_f32_16x16x32_bf16(
              kf2[lks][kk], qf[qs][kk], st[lks], 0, 0, 0);

      // P = exp2(s*log2e/8) (unmasked; scores bounded), pack to bf16
      float pr[8];
#pragma unroll
      for (int lks = 0; lks < 2; ++lks)
#pragma unroll
        for (int r = 0; r < 4; ++r)
          pr[lks * 4 + r] = __builtin_exp2f(st[lks][r] * 0.18033688f);
      u32 X0, X1, Y0, Y1;
      asm("v_cvt_pk_bf16_f32 %0, %1, %2" : "=v"(X0) : "v"(pr[0]), "v"(pr[1]));
      asm("v_cvt_pk_bf16_f32 %0, %1, %2" : "=v"(X1) : "v"(pr[2]), "v"(pr[3]));
      asm("v_cvt_pk_bf16_f32 %0, %1, %2" : "=v"(Y0) : "v"(pr[4]), "v"(pr[5]));
      asm("v_cvt_pk_bf16_f32 %0, %1, %2" : "=v"(Y1) : "v"(pr[6]), "v"(pr[7]));
      asm("v_permlane32_swap_b32 %0, %1" : "+v"(X0), "+v"(Y0));
      asm("v_permlane32_swap_b32 %0, %1" : "+v"(X1), "+v"(Y1));
      asm("v_permlane16_swap_b32 %0, %1" : "+v"(X0), "+v"(Y0));
      asm("v_permlane16_swap_b32 %0, %1" : "+v"(X1), "+v"(Y1));
      // mask: AND in the A-frag layout (zeroes masked-out keys exactly)
      const u32x4 am = qs ? am1 : am0;
      u32x4 paw;
      paw[0] = X0 & am[0];
      paw[1] = X1 & am[1];
      paw[2] = Y0 & am[2];
      paw[3] = Y1 & am[3];
      short8 pa = __builtin_bit_cast(short8, paw);
      // row-sum on the MFMA pipe (same C layout as o)
      osum[qs] = __builtin_amdgcn_mfma_f32_16x16x32_bf16(pa, ones, osum[qs], 0, 0, 0);
#pragma unroll
      for (int ds = 0; ds < 4; ++ds)
        o[qs][ds] = __builtin_amdgcn_mfma_f32_16x16x32_bf16(pa, vf[ds], o[qs][ds], 0, 0, 0);
    }

    Kp += 2048; Vp += 2048; M0 += 256; M1 += 256;
  }

  // epilogue: normalize (osum already in o's lane layout) and store
#pragma unroll
  for (int qs = 0; qs < 2; ++qs) {
    f32x4 inv4;
#pragma unroll
    for (int r = 0; r < 4; ++r) inv4[r] = 1.0f / osum[qs][r];
#pragma unroll
    for (int ds = 0; ds < 4; ++ds) {
      int d = ds * 16 + l;
#pragma unroll
      for (int r = 0; r < 4; ++r) {
        int node = (qb + qs) * 16 + j * 4 + r;
        out[(size_t)bs * 262144 + (size_t)node * 512 + h * 64 + d] = o[qs][ds][r] * inv4[r];
      }
    }
  }
}

// ---- launcher ----
extern "C" void kernel_launch(void* const* d_in, const int* in_sizes, int n_in,
                              void* d_out, int out_size, void* d_ws, size_t ws_size,
                              hipStream_t stream) {
  const float* x  = (const float*)d_in[0];
  const int*   e  = (const int*)d_in[1];
  const float* Wq = (const float*)d_in[2];
  const float* bq = (const float*)d_in[3];
  const float* Wk = (const float*)d_in[4];
  const float* bk = (const float*)d_in[5];
  const float* Wv = (const float*)d_in[6];
  const float* bv = (const float*)d_in[7];
  float* out = (float*)d_out;

  char* ws = (char*)d_ws;
  u16* xb   = (u16*)(ws);                 // 24576*512 bf16 = 25165824 B
  u16* wb   = (u16*)(ws + 25165824);      // 3*512*512 bf16 = 1572864 B
  u16* qkv  = (u16*)(ws + 26738688);      // 3*384*512*64 bf16 = 75497472 B
  u32* mfr  = (u32*)(ws + 102236160);     // 131072 u32 = 524288 B

  hipMemsetAsync(mfr, 0, 524288, stream);
  edge_mf<<<(NEDGES + 255) / 256, 256, 0, stream>>>(e, mfr);

  cast_all<<<2048, 256, 0, stream>>>(x, Wq, Wk, Wv, xb, wb);

  qkv_gemm<<<2304, 256, 0, stream>>>(xb, wb, bq, bk, bv, qkv);
  attn_kernel<<<1536, 256, 0, stream>>>(qkv, mfr, out);
}